// Round 13
// baseline (24977.803 us; speedup 1.0000x reference)
//
#include <hip/hip_runtime.h>
#include <math.h>

typedef unsigned short u16;
typedef __attribute__((ext_vector_type(8))) short bf16x8;
typedef __attribute__((ext_vector_type(4))) float f32x4;

#define MFMA(a, b, c) __builtin_amdgcn_mfma_f32_16x16x32_bf16(a, b, c, 0, 0, 0)

#define Bsz 512
#define Tsz 128
#define Dsz 256
#define CSs 10
#define Hsz 384
#define Gsz 1542
#define HSz 64
#define Gp  1568
#define NGT 98       // Gp/16
#define KTH 12       // 384/32
#define KTX 8        // 256/32
#define KTC 120      // 3840/32
#define NRG 32       // scan blocks, 16 batch rows each
#define XOP 1580     // s_xo row stride (floats)

// ---------------- ws layout (byte offsets) ----------------
constexpr size_t O_WPK  = 0;                                   // u16 98*12*2*512
constexpr size_t O_XWPK = O_WPK  + 2ull*NGT*KTH*2*512;         // u16 98*8*2*512
constexpr size_t O_CPK  = O_XWPK + 2ull*NGT*KTX*2*512;         // u16 24*120*512
constexpr size_t O_SPK  = O_CPK  + 2ull*24*KTC*512;            // u16 4*12*2*512
constexpr size_t O_RPK  = O_SPK  + 2ull*4*KTH*2*512;           // u16 24*2*2*512
constexpr size_t O_BC   = O_RPK  + 2ull*24*2*2*512;            // f32 Gp
constexpr size_t O_WT   = O_BC + 4ull*Gp;                      // f32 Gp
constexpr size_t O_HBF  = (O_WT + 4ull*Gp + 255) & ~(size_t)255;  // u16 B*T*H (50 MB)
constexpr size_t O_XPK  = O_HBF + 2ull*Bsz*Tsz*Hsz;            // u16 (67 MB)

__device__ __forceinline__ u16 f2bf(float f) {
    unsigned u = __float_as_uint(f);
    unsigned r = (u + 0x7FFFu + ((u >> 16) & 1u)) >> 16;
    return (u16)r;
}
__device__ __forceinline__ float bf2f(u16 v) {
    return __uint_as_float(((unsigned)v) << 16);
}
__device__ __forceinline__ float sigm(float v) { return 1.f / (1.f + expf(-v)); }

__global__ __launch_bounds__(256) void build_w(const float* __restrict__ kW,
                                               const float* __restrict__ kb,
                                               const float* __restrict__ rW,
                                               const float* __restrict__ rb,
                                               const float* __restrict__ sW,
                                               const float* __restrict__ rsW,
                                               u16* __restrict__ wpk,
                                               u16* __restrict__ xwpk,
                                               u16* __restrict__ spk,
                                               u16* __restrict__ rpk,
                                               float* __restrict__ bc,
                                               float* __restrict__ wt) {
    const int N1 = Gp * 384, N2 = Gp * 256, N3 = 64 * 384, N4 = 384 * 64;
    int idx = blockIdx.x * 256 + threadIdx.x;
    if (idx < N1) {
        int g = idx / 384, k = idx % 384;
        float v = (g < Gsz) ? rW[g * (Hsz + 1) + k] : 0.f;
        u16 hi = f2bf(v), lo = f2bf(v - bf2f(hi));
        size_t fo = ((size_t)((g >> 4) * KTH + (k >> 5)) * 2) * 512;
        int pos = ((g & 15) | (((k >> 3) & 3) << 4)) * 8 + (k & 7);
        wpk[fo + pos] = hi; wpk[fo + 512 + pos] = lo;
    } else if (idx < N1 + N2) {
        int i = idx - N1;
        int g = i / 256, k = i % 256;
        float v = (g < Gsz) ? kW[g * (Dsz + 1) + k] : 0.f;
        u16 hi = f2bf(v), lo = f2bf(v - bf2f(hi));
        size_t fo = ((size_t)((g >> 4) * KTX + (k >> 5)) * 2) * 512;
        int pos = ((g & 15) | (((k >> 3) & 3) << 4)) * 8 + (k & 7);
        xwpk[fo + pos] = hi; xwpk[fo + 512 + pos] = lo;
    } else if (idx < N1 + N2 + N3) {
        int i = idx - N1 - N2;
        int g = i / 384, k = i % 384;              // g<64
        float v = sW[g * Hsz + k];
        u16 hi = f2bf(v), lo = f2bf(v - bf2f(hi));
        size_t fo = ((size_t)((g >> 4) * KTH + (k >> 5)) * 2) * 512;
        int pos = ((g & 15) | (((k >> 3) & 3) << 4)) * 8 + (k & 7);
        spk[fo + pos] = hi; spk[fo + 512 + pos] = lo;
    } else if (idx < N1 + N2 + N3 + N4) {
        int i = idx - N1 - N2 - N3;
        int g = i / 64, k = i % 64;                // g<384
        float v = rsW[g * HSz + k];
        u16 hi = f2bf(v), lo = f2bf(v - bf2f(hi));
        size_t fo = ((size_t)((g >> 4) * 2 + (k >> 5)) * 2) * 512;
        int pos = ((g & 15) | (((k >> 3) & 3) << 4)) * 8 + (k & 7);
        rpk[fo + pos] = hi; rpk[fo + 512 + pos] = lo;
    } else if (idx < N1 + N2 + N3 + N4 + Gsz) {
        int g = idx - N1 - N2 - N3 - N4;
        bc[g] = kb[g] + rb[g];
        wt[g] = kW[g * (Dsz + 1) + Dsz] + rW[g * (Hsz + 1) + Hsz];
    }
}

__global__ __launch_bounds__(256) void pack_x(const float* __restrict__ x,
                                              u16* __restrict__ xpk) {
    int idx = blockIdx.x * 256 + threadIdx.x;
    int k = idx & 255, b = (idx >> 8) & 511, t = idx >> 17;
    float v = x[((size_t)b * Tsz + t) * Dsz + k];
    u16 hi = f2bf(v), lo = f2bf(v - bf2f(hi));
    size_t fo = (((size_t)t * 32 + (b >> 4)) * KTX + (k >> 5)) * 2 * 512;
    int pos = ((b & 15) | (((k >> 3) & 3) << 4)) * 8 + (k & 7);
    xpk[fo + pos] = hi;
    xpk[fo + 512 + pos] = lo;
}

__global__ __launch_bounds__(256) void pack_cw(const float* __restrict__ cW,
                                               u16* __restrict__ cpk) {
    int idx = blockIdx.x * 256 + threadIdx.x;
    if (idx >= Hsz * Hsz * CSs) return;
    int o = idx / (Hsz * CSs), k = idx % (Hsz * CSs);
    size_t fo = ((size_t)(o >> 4) * KTC + (k >> 5)) * 512;
    int pos = ((o & 15) | (((k >> 3) & 3) << 4)) * 8 + (k & 7);
    cpk[fo + pos] = f2bf(cW[idx]);
}

// ---- phase 1: serial recurrence. 32 blocks x 16 rows x 8 waves. ----
// Per g-tile: batch-issue ALL 40 B-loads into registers (160 VGPR, static
// indices) BEFORE the MFMA chain -> ~40 outstanding loads/wave instead of ~2.
__global__ __launch_bounds__(512, 2) void scan(const float* __restrict__ tme,
                                               char* __restrict__ ws,
                                               float* __restrict__ out) {
    const u16* wpk  = (const u16*)(ws + O_WPK);
    const u16* xwpk = (const u16*)(ws + O_XWPK);
    const float* bc = (const float*)(ws + O_BC);
    const float* wt = (const float*)(ws + O_WT);
    const u16* xpk  = (const u16*)(ws + O_XPK);

    int rg = blockIdx.x;
    u16* hbf = (u16*)(ws + O_HBF);

    float* out_seq  = out + (size_t)Bsz * Hsz;
    float* out_dist = out_seq + (size_t)Bsz * Tsz * Hsz;

    int tid = threadIdx.x;
    int wave = tid >> 6, lane = tid & 63, l15 = lane & 15, lk = lane >> 4;
    int b0 = rg * 16;

    __shared__ float s_xo[16][XOP];            // 101,120 B
    __shared__ u16   s_hpk[KTH][2][512];       // 24,576 B
    __shared__ u16   s_xa[2][16 * 512];        // 32,768 B   (x frags, dbuf)

    for (int i = tid; i < KTH * 2 * 256; i += 512) ((unsigned*)s_hpk)[i] = 0u;
    // stage x(0): wave w copies frags 2w, 2w+1
    {
        const u16* xs = xpk + ((size_t)(0 * 32 + rg) * KTX * 2) * 512;
        #pragma unroll
        for (int f = 0; f < 2; ++f) {
            int fr = wave * 2 + f;
            *(bf16x8*)&s_xa[0][fr * 512 + lane * 8] =
                *(const bf16x8*)(xs + (size_t)fr * 512 + lane * 8);
        }
    }
    float cregs[12] = {};
    __syncthreads();

    for (int t = 0; t < Tsz; ++t) {
        // ---------- phase A: xo = x(t)@kW + h(t-1)@rW, all 98 g-tiles ----------
        {
            if (t + 1 < Tsz) {
                const u16* xs = xpk + ((size_t)((t + 1) * 32 + rg) * KTX * 2) * 512;
                #pragma unroll
                for (int f = 0; f < 2; ++f) {
                    int fr = wave * 2 + f;
                    *(bf16x8*)&s_xa[(t + 1) & 1][fr * 512 + lane * 8] =
                        *(const bf16x8*)(xs + (size_t)fr * 512 + lane * 8);
                }
            }
            const u16* xcur = s_xa[t & 1];
            auto tile = [&](int gt) {
                // ---- batch-issue all 40 B loads (independent, static regs) ----
                bf16x8 wbh[KTH], wbl[KTH], xbh[KTX], xbl[KTX];
                #pragma unroll
                for (int kt = 0; kt < KTH; ++kt) {
                    size_t fb = ((size_t)(gt * KTH + kt) * 2) * 512 + lane * 8;
                    wbh[kt] = *(const bf16x8*)(wpk + fb);
                    wbl[kt] = *(const bf16x8*)(wpk + fb + 512);
                }
                #pragma unroll
                for (int kt = 0; kt < KTX; ++kt) {
                    size_t fb = ((size_t)(gt * KTX + kt) * 2) * 512 + lane * 8;
                    xbh[kt] = *(const bf16x8*)(xwpk + fb);
                    xbl[kt] = *(const bf16x8*)(xwpk + fb + 512);
                }
                // ---- MFMA chain (A frags re-read from LDS) ----
                f32x4 acc = {};
                #pragma unroll
                for (int kt = 0; kt < KTH; ++kt) {
                    bf16x8 ah = *(const bf16x8*)&s_hpk[kt][0][lane * 8];
                    bf16x8 al = *(const bf16x8*)&s_hpk[kt][1][lane * 8];
                    acc = MFMA(ah, wbh[kt], acc);
                    acc = MFMA(ah, wbl[kt], acc);
                    acc = MFMA(al, wbh[kt], acc);
                }
                #pragma unroll
                for (int kt = 0; kt < KTX; ++kt) {
                    bf16x8 xh = *(const bf16x8*)&xcur[(kt * 2) * 512 + lane * 8];
                    bf16x8 xl = *(const bf16x8*)&xcur[(kt * 2 + 1) * 512 + lane * 8];
                    acc = MFMA(xh, xbh[kt], acc);
                    acc = MFMA(xh, xbl[kt], acc);
                    acc = MFMA(xl, xbh[kt], acc);
                }
                int col = gt * 16 + l15;
                #pragma unroll
                for (int j = 0; j < 4; ++j)
                    s_xo[lk * 4 + j][col] = acc[j];
            };
            #pragma unroll
            for (int ti = 0; ti < 12; ++ti)
                tile(wave + (ti << 3));
            if (wave < 2) tile(96 + wave);
        }
        __syncthreads();

        // ---------- cell(t): 2 rows per wave (half-wave each), 12 ch/lane ----------
        {
            int r = wave * 2 + (lane >> 5);
            int c32 = lane & 31;
            int b = b0 + r;
            float tv = tme[b * Tsz + t];
            float zf[6];
            #pragma unroll
            for (int g = 0; g < 6; ++g)
                zf[g] = s_xo[r][g] + bc[g] + tv * wt[g];
            float m = fmaxf(zf[0], fmaxf(zf[1], zf[2]));
            float e0 = expf(zf[0] - m), e1 = expf(zf[1] - m), e2 = expf(zf[2] - m);
            float inv = 1.f / (e0 + e1 + e2);
            float fm0 = e0 * inv, fm1 = fm0 + e1 * inv;
            float mw = fmaxf(zf[3], fmaxf(zf[4], zf[5]));
            float f0 = expf(zf[3] - mw), f1 = expf(zf[4] - mw), f2 = expf(zf[5] - mw);
            float invw = 1.f / (f0 + f1 + f2);
            float im2 = f2 * invw, im1 = f1 * invw + im2;
            if (c32 == 0)
                out_dist[(size_t)t * Bsz + b] = 1.f - (fm0 + fm1 + 1.f) * (1.f / 3.f);
            #pragma unroll
            for (int i = 0; i < 12; ++i) {
                int ch = i * 32 + c32;
                const int l = i >> 2;                 // static per unrolled i
                float fm = (l == 0) ? fm0 : ((l == 1) ? fm1 : 1.f);
                float im = (l == 0) ? 1.f : ((l == 1) ? im1 : im2);
                int g0 = 6 + ch, g1 = g0 + Hsz, g2 = g0 + 2 * Hsz, g3 = g0 + 3 * Hsz;
                float fg = sigm(s_xo[r][g0] + bc[g0] + tv * wt[g0]);
                float ig = sigm(s_xo[r][g1] + bc[g1] + tv * wt[g1]);
                float og = sigm(s_xo[r][g2] + bc[g2] + tv * wt[g2]);
                float ci = tanhf(s_xo[r][g3] + bc[g3] + tv * wt[g3]);
                float cl = cregs[i];
                float ov = fm * im;
                float cn = ov * (fg * cl + ig * ci) + (fm - ov) * cl + (im - ov) * ci;
                float hn = og * tanhf(cn);
                cregs[i] = cn;
                u16 hh = f2bf(hn);
                u16 hl = f2bf(hn - bf2f(hh));
                int pos = (r | (((ch >> 3) & 3) << 4)) * 8 + (ch & 7);
                s_hpk[ch >> 5][0][pos] = hh;
                s_hpk[ch >> 5][1][pos] = hl;
                size_t oi = ((size_t)b * Tsz + t) * Hsz + ch;
                out_seq[oi] = hn;          // h (f32) — post adds theme*conv
                hbf[oi] = hh;              // h (bf16) for conv A-build
            }
        }
        __syncthreads();
    }
}

// ---- phase 2: fully parallel over (b, t). Block = (b, 16 t's). ----
__global__ __launch_bounds__(512, 1) void post(const float* __restrict__ sb,
                                               const float* __restrict__ rsb,
                                               const float* __restrict__ cb,
                                               char* __restrict__ ws,
                                               float* __restrict__ out) {
    const u16* cpk = (const u16*)(ws + O_CPK);
    const u16* spk = (const u16*)(ws + O_SPK);
    const u16* rpk = (const u16*)(ws + O_RPK);
    const u16* hbf = (const u16*)(ws + O_HBF);

    float* out_last = out;
    float* out_seq  = out + (size_t)Bsz * Hsz;
    const float* out_dist = out_seq + (size_t)Bsz * Tsz * Hsz;

    int b = blockIdx.x, t0 = blockIdx.y * 16;
    int tid = threadIdx.x;
    int wave = tid >> 6, lane = tid & 63, l15 = lane & 15, lk = lane >> 4;

    __shared__ u16 s_apk[KTC][512];            // 122,880 B
    __shared__ u16 s_tpk[KTH * 2][512];        // 24,576 B
    __shared__ float th1s[16][68];
    __shared__ float s_ld[16][CSs];

    if (tid < 16) {
        int r = tid;
        float vals[CSs];
        float cum = 0.f;
        #pragma unroll
        for (int j = 0; j < CSs; ++j) {
            int tp = t0 + r - 9 + j;
            float d = (tp < 0) ? 0.f : out_dist[(size_t)tp * Bsz + b];
            cum += d;
            vals[j] = cum;
        }
        float mx = vals[0];
        #pragma unroll
        for (int j = 1; j < CSs; ++j) mx = fmaxf(mx, vals[j]);
        float sum = 0.f;
        #pragma unroll
        for (int j = 0; j < CSs; ++j) { vals[j] = expf(vals[j] - mx); sum += vals[j]; }
        float invs = 1.f / sum;
        #pragma unroll
        for (int j = 0; j < CSs; ++j) s_ld[r][j] = vals[j] * invs;
    }
    __syncthreads();

    // A-build: av[r][k=ch*10+j] = h(b,t0+r-9+j)[ch] * ld[r][j]; thm = mean_j
    for (int u = tid; u < 768; u += 512) {
        int r = u / 48, c8 = u % 48, ch0 = c8 * 8;
        float acc[8] = {0.f, 0.f, 0.f, 0.f, 0.f, 0.f, 0.f, 0.f};
        #pragma unroll
        for (int j = 0; j < CSs; ++j) {
            int tp = t0 + r - 9 + j;
            float ldv = s_ld[r][j];
            if (tp >= 0) {
                bf16x8 hv = *(const bf16x8*)(hbf + ((size_t)b * Tsz + tp) * Hsz + ch0);
                #pragma unroll
                for (int e = 0; e < 8; ++e) {
                    float av = bf2f((u16)hv[e]) * ldv;
                    int k = (ch0 + e) * CSs + j;
                    s_apk[k >> 5][(r | (((k >> 3) & 3) << 4)) * 8 + (k & 7)] = f2bf(av);
                    acc[e] += av;
                }
            } else {
                #pragma unroll
                for (int e = 0; e < 8; ++e) {
                    int k = (ch0 + e) * CSs + j;
                    s_apk[k >> 5][(r | (((k >> 3) & 3) << 4)) * 8 + (k & 7)] = 0;
                }
            }
        }
        int pos0 = (r | (((ch0 >> 3) & 3) << 4)) * 8;
        int kt2 = (ch0 >> 5) * 2;
        #pragma unroll
        for (int e = 0; e < 8; ++e) {
            float thm = acc[e] * 0.1f;
            u16 th = f2bf(thm), tl = f2bf(thm - bf2f(th));
            s_tpk[kt2][pos0 + e] = th;
            s_tpk[kt2 + 1][pos0 + e] = tl;
        }
    }
    __syncthreads();

    // conv MFMA (24 ot over 8 waves) + theme stage 1 (waves 0-3)
    f32x4 cacc[3] = {};
    for (int kt = 0; kt < KTC; ++kt) {
        bf16x8 a = *(const bf16x8*)&s_apk[kt][lane * 8];
        #pragma unroll
        for (int i = 0; i < 3; ++i) {
            int ot = wave * 3 + i;
            bf16x8 bv = *(const bf16x8*)(cpk + ((size_t)(ot * KTC + kt)) * 512 + lane * 8);
            cacc[i] = MFMA(a, bv, cacc[i]);
        }
    }
    if (wave < 4) {
        f32x4 a1 = {};
        for (int kt = 0; kt < KTH; ++kt) {
            bf16x8 ah = *(const bf16x8*)&s_tpk[kt * 2][lane * 8];
            bf16x8 al = *(const bf16x8*)&s_tpk[kt * 2 + 1][lane * 8];
            size_t bb = ((size_t)(wave * KTH + kt) * 2) * 512 + lane * 8;
            bf16x8 bh = *(const bf16x8*)(spk + bb);
            bf16x8 bl = *(const bf16x8*)(spk + bb + 512);
            a1 = MFMA(ah, bh, a1);
            a1 = MFMA(ah, bl, a1);
            a1 = MFMA(al, bh, a1);
        }
        int col = wave * 16 + l15;
        #pragma unroll
        for (int j = 0; j < 4; ++j)
            th1s[lk * 4 + j][col] = fmaxf(a1[j] + sb[col], 0.f);
    }
    __syncthreads();

    // theme stage 2 + epilogue: out = sigm(mlp)*(conv+cb) + h  (h already in out_seq)
    bf16x8 ah2[2], al2[2];
    #pragma unroll
    for (int kt = 0; kt < 2; ++kt) {
        bf16x8 zh, zl;
        #pragma unroll
        for (int e = 0; e < 8; ++e) {
            float v = th1s[l15][kt * 32 + lk * 8 + e];
            u16 hi = f2bf(v);
            zh[e] = (short)hi;
            zl[e] = (short)f2bf(v - bf2f(hi));
        }
        ah2[kt] = zh; al2[kt] = zl;
    }
    #pragma unroll
    for (int i = 0; i < 3; ++i) {
        int ot = wave * 3 + i;
        f32x4 a2 = {};
        #pragma unroll
        for (int kt = 0; kt < 2; ++kt) {
            size_t bb = ((size_t)(ot * 2 + kt) * 2) * 512 + lane * 8;
            bf16x8 bh = *(const bf16x8*)(rpk + bb);
            bf16x8 bl = *(const bf16x8*)(rpk + bb + 512);
            a2 = MFMA(ah2[kt], bh, a2);
            a2 = MFMA(ah2[kt], bl, a2);
            a2 = MFMA(al2[kt], bh, a2);
        }
        int col = ot * 16 + l15;
        #pragma unroll
        for (int j = 0; j < 4; ++j) {
            int row = lk * 4 + j;
            int tt = t0 + row;
            size_t oi = ((size_t)b * Tsz + tt) * Hsz + col;
            float convv = cacc[i][j] + cb[col];
            float th = sigm(a2[j] + rsb[col]);
            float val = th * convv + out_seq[oi];
            out_seq[oi] = val;
            if (tt == Tsz - 1) out_last[(size_t)b * Hsz + col] = val;
        }
    }
}

extern "C" void kernel_launch(void* const* d_in, const int* in_sizes, int n_in,
                              void* d_out, int out_size, void* d_ws, size_t ws_size,
                              hipStream_t stream) {
    const float* x   = (const float*)d_in[0];
    const float* tme = (const float*)d_in[1];
    const float* kW  = (const float*)d_in[2];
    const float* kb  = (const float*)d_in[3];
    const float* rW  = (const float*)d_in[4];
    const float* rb  = (const float*)d_in[5];
    const float* sW  = (const float*)d_in[6];
    const float* sb  = (const float*)d_in[7];
    const float* rsW = (const float*)d_in[8];
    const float* rsb = (const float*)d_in[9];
    const float* cW  = (const float*)d_in[10];
    const float* cb  = (const float*)d_in[11];

    char* wsb = (char*)d_ws;
    float* outp = (float*)d_out;

    u16* wpk  = (u16*)(wsb + O_WPK);
    u16* xwpk = (u16*)(wsb + O_XWPK);
    u16* cpk  = (u16*)(wsb + O_CPK);
    u16* spk  = (u16*)(wsb + O_SPK);
    u16* rpk  = (u16*)(wsb + O_RPK);
    float* bc = (float*)(wsb + O_BC);
    float* wt = (float*)(wsb + O_WT);
    u16* xpk  = (u16*)(wsb + O_XPK);

    {
        int nW = Gp * 384 + Gp * 256 + 64 * 384 + 384 * 64 + Gsz;
        build_w<<<(nW + 255) / 256, 256, 0, stream>>>(kW, kb, rW, rb, sW, rsW,
                                                      wpk, xwpk, spk, rpk, bc, wt);
    }
    pack_x<<<(Tsz * Bsz * Dsz) / 256, 256, 0, stream>>>(x, xpk);
    pack_cw<<<(Hsz * Hsz * CSs + 255) / 256, 256, 0, stream>>>(cW, cpk);

    scan<<<NRG, 512, 0, stream>>>(tme, wsb, outp);
    post<<<dim3(Bsz, Tsz / 16), 512, 0, stream>>>(sb, rsb, cb, wsb, outp);
}

// Round 14
// 4947.263 us; speedup vs baseline: 5.0488x; 5.0488x over previous
//
#include <hip/hip_runtime.h>
#include <math.h>

typedef unsigned short u16;
typedef __attribute__((ext_vector_type(8))) short bf16x8;
typedef __attribute__((ext_vector_type(4))) float f32x4;

#define MFMA(a, b, c) __builtin_amdgcn_mfma_f32_16x16x32_bf16(a, b, c, 0, 0, 0)

#define Bsz 512
#define Tsz 128
#define Dsz 256
#define CSs 10
#define Hsz 384
#define Gsz 1542
#define HSz 64
#define Gp  1568
#define NGT 98       // Gp/16
#define KTH 12       // 384/32
#define KTX 8        // 256/32
#define KTC 120      // 3840/32

// ---------------- ws layout (byte offsets) ----------------
constexpr size_t O_WPK  = 0;                                   // u16 98*12*2*512
constexpr size_t O_XWPK = O_WPK  + 2ull*NGT*KTH*2*512;         // u16 98*8*2*512
constexpr size_t O_CPK  = O_XWPK + 2ull*NGT*KTX*2*512;         // u16 24*120*512
constexpr size_t O_SPK  = O_CPK  + 2ull*24*KTC*512;            // u16 4*12*2*512
constexpr size_t O_RPK  = O_SPK  + 2ull*4*KTH*2*512;           // u16 24*2*2*512
constexpr size_t O_BC   = O_RPK  + 2ull*24*2*2*512;            // f32 Gp
constexpr size_t O_WT   = O_BC + 4ull*Gp;                      // f32 Gp
constexpr size_t O_HBF  = (O_WT + 4ull*Gp + 255) & ~(size_t)255;  // u16 B*T*H (50 MB)
constexpr size_t O_XPK  = O_HBF + 2ull*Bsz*Tsz*Hsz;            // u16 (67 MB)
constexpr size_t O_XWB  = O_XPK + 2ull*Tsz*32*KTX*2*512;       // f32 B*Gp (xw)
constexpr size_t O_HWB  = O_XWB + 4ull*Bsz*Gp;                 // f32 B*Gp (hw)
constexpr size_t O_HPKG = O_HWB + 4ull*Bsz*Gp;                 // u16 32*12*2*512 (zeroed)
constexpr size_t O_CFB  = O_HPKG + 2ull*32*KTH*2*512;          // f32 B*H (zeroed)
constexpr size_t ZERO_BEG = O_HPKG;
constexpr size_t ZERO_END = O_CFB + 4ull*Bsz*Hsz;

__device__ __forceinline__ u16 f2bf(float f) {
    unsigned u = __float_as_uint(f);
    unsigned r = (u + 0x7FFFu + ((u >> 16) & 1u)) >> 16;
    return (u16)r;
}
__device__ __forceinline__ float bf2f(u16 v) {
    return __uint_as_float(((unsigned)v) << 16);
}
__device__ __forceinline__ float sigm(float v) { return 1.f / (1.f + expf(-v)); }

__global__ __launch_bounds__(256) void zero4(float4* __restrict__ p, int n4) {
    int i = blockIdx.x * 256 + threadIdx.x;
    if (i < n4) p[i] = make_float4(0.f, 0.f, 0.f, 0.f);
}

__global__ __launch_bounds__(256) void build_w(const float* __restrict__ kW,
                                               const float* __restrict__ kb,
                                               const float* __restrict__ rW,
                                               const float* __restrict__ rb,
                                               const float* __restrict__ sW,
                                               const float* __restrict__ rsW,
                                               u16* __restrict__ wpk,
                                               u16* __restrict__ xwpk,
                                               u16* __restrict__ spk,
                                               u16* __restrict__ rpk,
                                               float* __restrict__ bc,
                                               float* __restrict__ wt) {
    const int N1 = Gp * 384, N2 = Gp * 256, N3 = 64 * 384, N4 = 384 * 64;
    int idx = blockIdx.x * 256 + threadIdx.x;
    if (idx < N1) {
        int g = idx / 384, k = idx % 384;
        float v = (g < Gsz) ? rW[g * (Hsz + 1) + k] : 0.f;
        u16 hi = f2bf(v), lo = f2bf(v - bf2f(hi));
        size_t fo = ((size_t)((g >> 4) * KTH + (k >> 5)) * 2) * 512;
        int pos = ((g & 15) | (((k >> 3) & 3) << 4)) * 8 + (k & 7);
        wpk[fo + pos] = hi; wpk[fo + 512 + pos] = lo;
    } else if (idx < N1 + N2) {
        int i = idx - N1;
        int g = i / 256, k = i % 256;
        float v = (g < Gsz) ? kW[g * (Dsz + 1) + k] : 0.f;
        u16 hi = f2bf(v), lo = f2bf(v - bf2f(hi));
        size_t fo = ((size_t)((g >> 4) * KTX + (k >> 5)) * 2) * 512;
        int pos = ((g & 15) | (((k >> 3) & 3) << 4)) * 8 + (k & 7);
        xwpk[fo + pos] = hi; xwpk[fo + 512 + pos] = lo;
    } else if (idx < N1 + N2 + N3) {
        int i = idx - N1 - N2;
        int g = i / 384, k = i % 384;              // g<64
        float v = sW[g * Hsz + k];
        u16 hi = f2bf(v), lo = f2bf(v - bf2f(hi));
        size_t fo = ((size_t)((g >> 4) * KTH + (k >> 5)) * 2) * 512;
        int pos = ((g & 15) | (((k >> 3) & 3) << 4)) * 8 + (k & 7);
        spk[fo + pos] = hi; spk[fo + 512 + pos] = lo;
    } else if (idx < N1 + N2 + N3 + N4) {
        int i = idx - N1 - N2 - N3;
        int g = i / 64, k = i % 64;                // g<384
        float v = rsW[g * HSz + k];
        u16 hi = f2bf(v), lo = f2bf(v - bf2f(hi));
        size_t fo = ((size_t)((g >> 4) * 2 + (k >> 5)) * 2) * 512;
        int pos = ((g & 15) | (((k >> 3) & 3) << 4)) * 8 + (k & 7);
        rpk[fo + pos] = hi; rpk[fo + 512 + pos] = lo;
    } else if (idx < N1 + N2 + N3 + N4 + Gsz) {
        int g = idx - N1 - N2 - N3 - N4;
        bc[g] = kb[g] + rb[g];
        wt[g] = kW[g * (Dsz + 1) + Dsz] + rW[g * (Hsz + 1) + Hsz];
    }
}

__global__ __launch_bounds__(256) void pack_x(const float* __restrict__ x,
                                              u16* __restrict__ xpk) {
    int idx = blockIdx.x * 256 + threadIdx.x;
    int k = idx & 255, b = (idx >> 8) & 511, t = idx >> 17;
    float v = x[((size_t)b * Tsz + t) * Dsz + k];
    u16 hi = f2bf(v), lo = f2bf(v - bf2f(hi));
    size_t fo = (((size_t)t * 32 + (b >> 4)) * KTX + (k >> 5)) * 2 * 512;
    int pos = ((b & 15) | (((k >> 3) & 3) << 4)) * 8 + (k & 7);
    xpk[fo + pos] = hi;
    xpk[fo + 512 + pos] = lo;
}

__global__ __launch_bounds__(256) void pack_cw(const float* __restrict__ cW,
                                               u16* __restrict__ cpk) {
    int idx = blockIdx.x * 256 + threadIdx.x;
    if (idx >= Hsz * Hsz * CSs) return;
    int o = idx / (Hsz * CSs), k = idx % (Hsz * CSs);
    size_t fo = ((size_t)(o >> 4) * KTC + (k >> 5)) * 512;
    int pos = ((o & 15) | (((k >> 3) & 3) << 4)) * 8 + (k & 7);
    cpk[fo + pos] = f2bf(cW[idx]);
}

// ---- per-step GEMM: bid<112 HW(t)=h(t-1)@rW^T -> hw; else XW(t)=x(t)@kW^T -> xw.
// 448 wave-units per part = 32 m-tiles x 14 n-slices (7 g-tiles of 16 each).
__global__ __launch_bounds__(256, 2) void gstep(char* __restrict__ ws, int t) {
    const u16* wpk  = (const u16*)(ws + O_WPK);
    const u16* xwpk = (const u16*)(ws + O_XWPK);
    const u16* hpk  = (const u16*)(ws + O_HPKG);
    const u16* xpk  = (const u16*)(ws + O_XPK);
    float* xw = (float*)(ws + O_XWB);
    float* hw = (float*)(ws + O_HWB);

    int bid = blockIdx.x;
    int wave = threadIdx.x >> 6, lane = threadIdx.x & 63;
    int l15 = lane & 15, lk = lane >> 4;
    int part = bid >= 112;
    int u = (part ? bid - 112 : bid) * 4 + wave;   // [0,448)
    int mt = u & 31, ns = u >> 5;                  // 32 x 14
    int nt0 = ns * 7;

    const u16* Asrc;
    const u16* Bsrc;
    int nkt;
    float* dst;
    if (!part) {
        Asrc = hpk + (size_t)mt * KTH * 2 * 512;
        Bsrc = wpk; nkt = KTH; dst = hw;
    } else {
        Asrc = xpk + ((size_t)(t * 32 + mt) * KTX * 2) * 512;
        Bsrc = xwpk; nkt = KTX; dst = xw;
    }

    f32x4 acc[7] = {};
    for (int kt = 0; kt < nkt; ++kt) {
        size_t ab = (size_t)(kt * 2) * 512 + lane * 8;
        bf16x8 ah = *(const bf16x8*)(Asrc + ab);
        bf16x8 al = *(const bf16x8*)(Asrc + ab + 512);
        #pragma unroll
        for (int ni = 0; ni < 7; ++ni) {
            size_t fb = ((size_t)((nt0 + ni) * nkt + kt) * 2) * 512 + lane * 8;
            bf16x8 bh = *(const bf16x8*)(Bsrc + fb);
            bf16x8 bl = *(const bf16x8*)(Bsrc + fb + 512);
            acc[ni] = MFMA(ah, bh, acc[ni]);
            acc[ni] = MFMA(ah, bl, acc[ni]);
            acc[ni] = MFMA(al, bh, acc[ni]);
        }
    }
    #pragma unroll
    for (int ni = 0; ni < 7; ++ni) {
        int col = (nt0 + ni) * 16 + l15;
        #pragma unroll
        for (int j = 0; j < 4; ++j) {
            int row = mt * 16 + lk * 4 + j;
            dst[(size_t)row * Gp + col] = acc[ni][j];
        }
    }
}

// ---- per-step cell: 32 blocks x 512 thr (16 rows x 32 lanes). No LDS. ----
__global__ __launch_bounds__(512) void cell(const float* __restrict__ tme,
                                            char* __restrict__ ws,
                                            float* __restrict__ out, int t) {
    const float* bc = (const float*)(ws + O_BC);
    const float* wt = (const float*)(ws + O_WT);
    const float* xw = (const float*)(ws + O_XWB);
    const float* hw = (const float*)(ws + O_HWB);
    float* cf = (float*)(ws + O_CFB);
    u16* hpk = (u16*)(ws + O_HPKG);
    u16* hbf = (u16*)(ws + O_HBF);

    float* out_seq  = out + (size_t)Bsz * Hsz;
    float* out_dist = out_seq + (size_t)Bsz * Tsz * Hsz;

    int tid = threadIdx.x;
    int r = tid >> 5, c32 = tid & 31;
    int b = blockIdx.x * 16 + r;
    const float* xa = xw + (size_t)b * Gp;
    const float* ha = hw + (size_t)b * Gp;
    float tv = tme[b * Tsz + t];

    float zf[6];
    #pragma unroll
    for (int g = 0; g < 6; ++g)
        zf[g] = xa[g] + ha[g] + bc[g] + tv * wt[g];
    float m = fmaxf(zf[0], fmaxf(zf[1], zf[2]));
    float e0 = expf(zf[0] - m), e1 = expf(zf[1] - m), e2 = expf(zf[2] - m);
    float inv = 1.f / (e0 + e1 + e2);
    float fm0 = e0 * inv, fm1 = fm0 + e1 * inv;
    float mw = fmaxf(zf[3], fmaxf(zf[4], zf[5]));
    float f0 = expf(zf[3] - mw), f1 = expf(zf[4] - mw), f2 = expf(zf[5] - mw);
    float invw = 1.f / (f0 + f1 + f2);
    float im2 = f2 * invw, im1 = f1 * invw + im2;
    if (c32 == 0)
        out_dist[(size_t)t * Bsz + b] = 1.f - (fm0 + fm1 + 1.f) * (1.f / 3.f);

    int mt = b >> 4;
    #pragma unroll
    for (int i = 0; i < 12; ++i) {
        int ch = i * 32 + c32;
        const int l = i >> 2;                 // static per unrolled i
        float fm = (l == 0) ? fm0 : ((l == 1) ? fm1 : 1.f);
        float im = (l == 0) ? 1.f : ((l == 1) ? im1 : im2);
        int g0 = 6 + ch, g1 = g0 + Hsz, g2 = g0 + 2 * Hsz, g3 = g0 + 3 * Hsz;
        float fg = sigm(xa[g0] + ha[g0] + bc[g0] + tv * wt[g0]);
        float ig = sigm(xa[g1] + ha[g1] + bc[g1] + tv * wt[g1]);
        float og = sigm(xa[g2] + ha[g2] + bc[g2] + tv * wt[g2]);
        float ci = tanhf(xa[g3] + ha[g3] + bc[g3] + tv * wt[g3]);
        float cl = cf[(size_t)b * Hsz + ch];
        float ov = fm * im;
        float cn = ov * (fg * cl + ig * ci) + (fm - ov) * cl + (im - ov) * ci;
        float hn = og * tanhf(cn);
        cf[(size_t)b * Hsz + ch] = cn;
        u16 hh = f2bf(hn);
        u16 hl = f2bf(hn - bf2f(hh));
        int pos = (r | (((ch >> 3) & 3) << 4)) * 8 + (ch & 7);
        size_t fo = ((size_t)(mt * KTH + (ch >> 5)) * 2) * 512;
        hpk[fo + pos] = hh;
        hpk[fo + 512 + pos] = hl;
        size_t oi = ((size_t)b * Tsz + t) * Hsz + ch;
        out_seq[oi] = hn;          // h (f32) — post adds theme*conv
        hbf[oi] = hh;              // h (bf16) for conv A-build
    }
}

// ---- phase 2: fully parallel over (b, t). Block = (b, 16 t's). ----
__global__ __launch_bounds__(512, 1) void post(const float* __restrict__ sb,
                                               const float* __restrict__ rsb,
                                               const float* __restrict__ cb,
                                               char* __restrict__ ws,
                                               float* __restrict__ out) {
    const u16* cpk = (const u16*)(ws + O_CPK);
    const u16* spk = (const u16*)(ws + O_SPK);
    const u16* rpk = (const u16*)(ws + O_RPK);
    const u16* hbf = (const u16*)(ws + O_HBF);

    float* out_last = out;
    float* out_seq  = out + (size_t)Bsz * Hsz;
    const float* out_dist = out_seq + (size_t)Bsz * Tsz * Hsz;

    int b = blockIdx.x, t0 = blockIdx.y * 16;
    int tid = threadIdx.x;
    int wave = tid >> 6, lane = tid & 63, l15 = lane & 15, lk = lane >> 4;

    __shared__ u16 s_apk[KTC][512];            // 122,880 B
    __shared__ u16 s_tpk[KTH * 2][512];        // 24,576 B
    __shared__ float th1s[16][68];
    __shared__ float s_ld[16][CSs];

    if (tid < 16) {
        int r = tid;
        float vals[CSs];
        float cum = 0.f;
        #pragma unroll
        for (int j = 0; j < CSs; ++j) {
            int tp = t0 + r - 9 + j;
            float d = (tp < 0) ? 0.f : out_dist[(size_t)tp * Bsz + b];
            cum += d;
            vals[j] = cum;
        }
        float mx = vals[0];
        #pragma unroll
        for (int j = 1; j < CSs; ++j) mx = fmaxf(mx, vals[j]);
        float sum = 0.f;
        #pragma unroll
        for (int j = 0; j < CSs; ++j) { vals[j] = expf(vals[j] - mx); sum += vals[j]; }
        float invs = 1.f / sum;
        #pragma unroll
        for (int j = 0; j < CSs; ++j) s_ld[r][j] = vals[j] * invs;
    }
    __syncthreads();

    // A-build: av[r][k=ch*10+j] = h(b,t0+r-9+j)[ch] * ld[r][j]; thm = mean_j
    for (int u = tid; u < 768; u += 512) {
        int r = u / 48, c8 = u % 48, ch0 = c8 * 8;
        float acc[8] = {0.f, 0.f, 0.f, 0.f, 0.f, 0.f, 0.f, 0.f};
        #pragma unroll
        for (int j = 0; j < CSs; ++j) {
            int tp = t0 + r - 9 + j;
            float ldv = s_ld[r][j];
            if (tp >= 0) {
                bf16x8 hv = *(const bf16x8*)(hbf + ((size_t)b * Tsz + tp) * Hsz + ch0);
                #pragma unroll
                for (int e = 0; e < 8; ++e) {
                    float av = bf2f((u16)hv[e]) * ldv;
                    int k = (ch0 + e) * CSs + j;
                    s_apk[k >> 5][(r | (((k >> 3) & 3) << 4)) * 8 + (k & 7)] = f2bf(av);
                    acc[e] += av;
                }
            } else {
                #pragma unroll
                for (int e = 0; e < 8; ++e) {
                    int k = (ch0 + e) * CSs + j;
                    s_apk[k >> 5][(r | (((k >> 3) & 3) << 4)) * 8 + (k & 7)] = 0;
                }
            }
        }
        int pos0 = (r | (((ch0 >> 3) & 3) << 4)) * 8;
        int kt2 = (ch0 >> 5) * 2;
        #pragma unroll
        for (int e = 0; e < 8; ++e) {
            float thm = acc[e] * 0.1f;
            u16 th = f2bf(thm), tl = f2bf(thm - bf2f(th));
            s_tpk[kt2][pos0 + e] = th;
            s_tpk[kt2 + 1][pos0 + e] = tl;
        }
    }
    __syncthreads();

    // conv MFMA (24 ot over 8 waves) + theme stage 1 (waves 0-3)
    f32x4 cacc[3] = {};
    for (int kt = 0; kt < KTC; ++kt) {
        bf16x8 a = *(const bf16x8*)&s_apk[kt][lane * 8];
        #pragma unroll
        for (int i = 0; i < 3; ++i) {
            int ot = wave * 3 + i;
            bf16x8 bv = *(const bf16x8*)(cpk + ((size_t)(ot * KTC + kt)) * 512 + lane * 8);
            cacc[i] = MFMA(a, bv, cacc[i]);
        }
    }
    if (wave < 4) {
        f32x4 a1 = {};
        for (int kt = 0; kt < KTH; ++kt) {
            bf16x8 ah = *(const bf16x8*)&s_tpk[kt * 2][lane * 8];
            bf16x8 al = *(const bf16x8*)&s_tpk[kt * 2 + 1][lane * 8];
            size_t bb = ((size_t)(wave * KTH + kt) * 2) * 512 + lane * 8;
            bf16x8 bh = *(const bf16x8*)(spk + bb);
            bf16x8 bl = *(const bf16x8*)(spk + bb + 512);
            a1 = MFMA(ah, bh, a1);
            a1 = MFMA(ah, bl, a1);
            a1 = MFMA(al, bh, a1);
        }
        int col = wave * 16 + l15;
        #pragma unroll
        for (int j = 0; j < 4; ++j)
            th1s[lk * 4 + j][col] = fmaxf(a1[j] + sb[col], 0.f);
    }
    __syncthreads();

    // theme stage 2 + epilogue: out = sigm(mlp)*(conv+cb) + h  (h already in out_seq)
    bf16x8 ah2[2], al2[2];
    #pragma unroll
    for (int kt = 0; kt < 2; ++kt) {
        bf16x8 zh, zl;
        #pragma unroll
        for (int e = 0; e < 8; ++e) {
            float v = th1s[l15][kt * 32 + lk * 8 + e];
            u16 hi = f2bf(v);
            zh[e] = (short)hi;
            zl[e] = (short)f2bf(v - bf2f(hi));
        }
        ah2[kt] = zh; al2[kt] = zl;
    }
    #pragma unroll
    for (int i = 0; i < 3; ++i) {
        int ot = wave * 3 + i;
        f32x4 a2 = {};
        #pragma unroll
        for (int kt = 0; kt < 2; ++kt) {
            size_t bb = ((size_t)(ot * 2 + kt) * 2) * 512 + lane * 8;
            bf16x8 bh = *(const bf16x8*)(rpk + bb);
            bf16x8 bl = *(const bf16x8*)(rpk + bb + 512);
            a2 = MFMA(ah2[kt], bh, a2);
            a2 = MFMA(ah2[kt], bl, a2);
            a2 = MFMA(al2[kt], bh, a2);
        }
        int col = ot * 16 + l15;
        #pragma unroll
        for (int j = 0; j < 4; ++j) {
            int row = lk * 4 + j;
            int tt = t0 + row;
            size_t oi = ((size_t)b * Tsz + tt) * Hsz + col;
            float convv = cacc[i][j] + cb[col];
            float th = sigm(a2[j] + rsb[col]);
            float val = th * convv + out_seq[oi];
            out_seq[oi] = val;
            if (tt == Tsz - 1) out_last[(size_t)b * Hsz + col] = val;
        }
    }
}

extern "C" void kernel_launch(void* const* d_in, const int* in_sizes, int n_in,
                              void* d_out, int out_size, void* d_ws, size_t ws_size,
                              hipStream_t stream) {
    const float* x   = (const float*)d_in[0];
    const float* tme = (const float*)d_in[1];
    const float* kW  = (const float*)d_in[2];
    const float* kb  = (const float*)d_in[3];
    const float* rW  = (const float*)d_in[4];
    const float* rb  = (const float*)d_in[5];
    const float* sW  = (const float*)d_in[6];
    const float* sb  = (const float*)d_in[7];
    const float* rsW = (const float*)d_in[8];
    const float* rsb = (const float*)d_in[9];
    const float* cW  = (const float*)d_in[10];
    const float* cb  = (const float*)d_in[11];

    char* wsb = (char*)d_ws;
    float* outp = (float*)d_out;

    u16* wpk  = (u16*)(wsb + O_WPK);
    u16* xwpk = (u16*)(wsb + O_XWPK);
    u16* cpk  = (u16*)(wsb + O_CPK);
    u16* spk  = (u16*)(wsb + O_SPK);
    u16* rpk  = (u16*)(wsb + O_RPK);
    float* bc = (float*)(wsb + O_BC);
    float* wt = (float*)(wsb + O_WT);
    u16* xpk  = (u16*)(wsb + O_XPK);

    zero4<<<(int)((ZERO_END - ZERO_BEG) / 16 + 255) / 256, 256, 0, stream>>>(
        (float4*)(wsb + ZERO_BEG), (int)((ZERO_END - ZERO_BEG) / 16));
    {
        int nW = Gp * 384 + Gp * 256 + 64 * 384 + 384 * 64 + Gsz;
        build_w<<<(nW + 255) / 256, 256, 0, stream>>>(kW, kb, rW, rb, sW, rsW,
                                                      wpk, xwpk, spk, rpk, bc, wt);
    }
    pack_x<<<(Tsz * Bsz * Dsz) / 256, 256, 0, stream>>>(x, xpk);
    pack_cw<<<(Hsz * Hsz * CSs + 255) / 256, 256, 0, stream>>>(cW, cpk);

    for (int t = 0; t < Tsz; ++t) {
        gstep<<<224, 256, 0, stream>>>(wsb, t);
        cell<<<32, 512, 0, stream>>>(tme, wsb, outp, t);
    }
    post<<<dim3(Bsz, Tsz / 16), 512, 0, stream>>>(sb, rsb, cb, wsb, outp);
}